// Round 4
// baseline (446.209 us; speedup 1.0000x reference)
//
#include <hip/hip_runtime.h>
#include <math.h>

#define N_NODES 100000
#define N_EDGES 1600000
#define IN_DIM 128
#define HID_DIM 64
#define OUT_DIM 40

#define NPAD 102400
#define SCAN_CHUNK 1024
#define NB ((N_NODES + SCAN_CHUNK - 1) / SCAN_CHUNK)  // 98 blocks

#define FILL_PASSES 4
#define FILL_CHUNK (N_NODES / FILL_PASSES)  // 25000: ~1.6MB csr window, L2-resident

// -------- workspace layout (int region first, then float region) --------
// ints:   cnt[NPAD] | cursor[NPAD] | row_start[NPAD] | blockSums[128] | csr[N_EDGES]
// floats: dinv[NPAD] | h1p[N*64] | z[N*64] | h2p[N*40]
// zeroed per launch: cnt + cursor (2*NPAD ints = 0.8 MB)

__global__ void count_kernel(const int* __restrict__ dst, int* __restrict__ cnt) {
    int e = blockIdx.x * blockDim.x + threadIdx.x;
    if (e < N_EDGES) atomicAdd(&cnt[dst[e]], 1);
}

__global__ void dinv_kernel(const int* __restrict__ cnt, float* __restrict__ dinv) {
    int i = blockIdx.x * blockDim.x + threadIdx.x;
    if (i < N_NODES) dinv[i] = rsqrtf((float)cnt[i] + 1.0f);
}

// exclusive scan, stage 1: per-block (1024 elements, 256 thr x 4) partial scan
__global__ __launch_bounds__(256) void scan_partial_kernel(const int* __restrict__ cnt,
                                                           int* __restrict__ excl,
                                                           int* __restrict__ blockSums) {
    __shared__ int lds[256];
    int base = blockIdx.x * SCAN_CHUNK;
    int t = threadIdx.x;
    int v[4];
    int s = 0;
    for (int k = 0; k < 4; ++k) {
        int idx = base + t * 4 + k;
        int c = (idx < N_NODES) ? cnt[idx] : 0;
        v[k] = s;
        s += c;
    }
    lds[t] = s;
    __syncthreads();
    for (int off = 1; off < 256; off <<= 1) {
        int val = (t >= off) ? lds[t - off] : 0;
        __syncthreads();
        lds[t] += val;
        __syncthreads();
    }
    int thread_excl = (t == 0) ? 0 : lds[t - 1];
    if (t == 255) blockSums[blockIdx.x] = lds[255];
    for (int k = 0; k < 4; ++k) {
        int idx = base + t * 4 + k;
        if (idx < N_NODES) excl[idx] = thread_excl + v[k];
    }
}

__global__ __launch_bounds__(128) void scan_blocksums_kernel(int* __restrict__ blockSums) {
    __shared__ int lds[128];
    int t = threadIdx.x;
    int v = (t < NB) ? blockSums[t] : 0;
    lds[t] = v;
    __syncthreads();
    for (int off = 1; off < 128; off <<= 1) {
        int val = (t >= off) ? lds[t - off] : 0;
        __syncthreads();
        lds[t] += val;
        __syncthreads();
    }
    int excl = (t == 0) ? 0 : lds[t - 1];
    if (t < NB) blockSums[t] = excl;
}

__global__ void scan_add_kernel(int* __restrict__ excl, const int* __restrict__ blockSums) {
    int idx = blockIdx.x * blockDim.x + threadIdx.x;
    if (idx < N_NODES) excl[idx] += blockSums[idx / SCAN_CHUNK];
}

// Windowed CSR fill: only edges with dst in [lo,hi) are placed this pass.
// Keeps the active csr segment (~1.6 MB) + cursor window L2-resident so
// scattered 4B writes coalesce into full-line writebacks.
__global__ void fill_window_kernel(const int* __restrict__ src, const int* __restrict__ dst,
                                   const int* __restrict__ row_start, int* __restrict__ cursor,
                                   int* __restrict__ csr, int lo, int hi) {
    int e = blockIdx.x * blockDim.x + threadIdx.x;
    if (e < N_EDGES) {
        int d = dst[e];
        if (d >= lo && d < hi) {
            int pos = row_start[d] + atomicAdd(&cursor[d], 1);
            csr[pos] = src[e];
        }
    }
}

// ---------------- gemm1: h1p[i][j] = dinv[i] * sum_k x[i][k] * W1[k][j] ----------------
#define G1_XS 36
__global__ __launch_bounds__(256) void gemm1_kernel(const float* __restrict__ x,
                                                    const float* __restrict__ W1,
                                                    const float* __restrict__ dinv,
                                                    float* __restrict__ h1p) {
    __shared__ float ws[IN_DIM * HID_DIM];   // 32 KB
    __shared__ float xT[IN_DIM * G1_XS];     // 18 KB
    int t = threadIdx.x;
    int nodeBase = blockIdx.x * 32;

    const float4* W4 = (const float4*)W1;
    float4* ws4 = (float4*)ws;
#pragma unroll
    for (int i = 0; i < 8; ++i) ws4[t + 256 * i] = W4[t + 256 * i];

    int kg = t & 31;
    int nd = t >> 5;
#pragma unroll
    for (int m = 0; m < 4; ++m) {
        int node = nd + 8 * m;
        const float* xr = x + (size_t)(nodeBase + node) * IN_DIM;
#pragma unroll
        for (int j = 0; j < 4; ++j) {
            xT[(kg + 32 * j) * G1_XS + node] = xr[kg + 32 * j];
        }
    }
    __syncthreads();

    int g = t >> 5;   // node group of 4
    int c = t & 31;   // col group of 2
    float a00 = 0.f, a01 = 0.f, a10 = 0.f, a11 = 0.f;
    float a20 = 0.f, a21 = 0.f, a30 = 0.f, a31 = 0.f;
#pragma unroll 4
    for (int k = 0; k < IN_DIM; ++k) {
        float4 xv = *(const float4*)&xT[k * G1_XS + 4 * g];
        float2 wv = *(const float2*)&ws[k * HID_DIM + 2 * c];
        a00 += xv.x * wv.x; a01 += xv.x * wv.y;
        a10 += xv.y * wv.x; a11 += xv.y * wv.y;
        a20 += xv.z * wv.x; a21 += xv.z * wv.y;
        a30 += xv.w * wv.x; a31 += xv.w * wv.y;
    }
    float r0[4] = {a00, a10, a20, a30};
    float r1[4] = {a01, a11, a21, a31};
#pragma unroll
    for (int i = 0; i < 4; ++i) {
        int n = nodeBase + 4 * g + i;
        float di = dinv[n];
        float2 o;
        o.x = r0[i] * di;
        o.y = r1[i] * di;
        *(float2*)&h1p[(size_t)n * HID_DIM + 2 * c] = o;
    }
}

// one wave per node: lanes = 64 hidden dims; gather-sum neighbor rows
__global__ __launch_bounds__(256) void agg1_kernel(const float* __restrict__ h1p,
                                                   const int* __restrict__ csr,
                                                   const int* __restrict__ row_start,
                                                   const int* __restrict__ cnt,
                                                   const float* __restrict__ dinv,
                                                   const float* __restrict__ b1,
                                                   float* __restrict__ z) {
    int w = blockIdx.x * 4 + (threadIdx.x >> 6);
    int j = threadIdx.x & 63;
    if (w >= N_NODES) return;
    int s0 = row_start[w];
    int n  = cnt[w];
    const int* cp = csr + s0;
    float acc = h1p[(size_t)w * HID_DIM + j];   // self loop
    int k = 0;
    for (; k + 4 <= n; k += 4) {
        int a = cp[k], b = cp[k + 1], c = cp[k + 2], d = cp[k + 3];
        float f0 = h1p[(size_t)a * HID_DIM + j];
        float f1 = h1p[(size_t)b * HID_DIM + j];
        float f2 = h1p[(size_t)c * HID_DIM + j];
        float f3 = h1p[(size_t)d * HID_DIM + j];
        acc += f0 + f1 + f2 + f3;
    }
    for (; k < n; ++k) acc += h1p[(size_t)cp[k] * HID_DIM + j];
    float v = acc * dinv[w] + b1[j];
    z[(size_t)w * HID_DIM + j] = v > 0.f ? v : 0.f;
}

// ---------------- gemm2: h2p[i][j] = dinv[i] * sum_k z[i][k] * W2[k][j] ----------------
#define G2_ZS 68
__global__ __launch_bounds__(256) void gemm2_kernel(const float* __restrict__ z,
                                                    const float* __restrict__ W2,
                                                    const float* __restrict__ dinv,
                                                    float* __restrict__ h2p) {
    __shared__ float ws[HID_DIM * OUT_DIM];  // 2560 floats
    __shared__ float zT[HID_DIM * G2_ZS];    // 4352 floats
    int t = threadIdx.x;
    int nodeBase = blockIdx.x * 64;

    const float4* W4 = (const float4*)W2;
    float4* ws4 = (float4*)ws;
    for (int i = t; i < (HID_DIM * OUT_DIM) / 4; i += 256) ws4[i] = W4[i];

    int kg = t & 31;
    int nd = t >> 5;
#pragma unroll
    for (int m = 0; m < 8; ++m) {
        int node = nd + 8 * m;
        int n = nodeBase + node;
        float v0 = 0.f, v1 = 0.f;
        if (n < N_NODES) {
            const float* zr = z + (size_t)n * HID_DIM;
            v0 = zr[kg];
            v1 = zr[kg + 32];
        }
        zT[kg * G2_ZS + node] = v0;
        zT[(kg + 32) * G2_ZS + node] = v1;
    }
    __syncthreads();

    int g = t >> 4;   // node group of 4
    int c = t & 15;   // col group of 4; active c<10
    if (c < 10) {
        float acc[4][4] = {};
#pragma unroll 4
        for (int k = 0; k < HID_DIM; ++k) {
            float4 zv = *(const float4*)&zT[k * G2_ZS + 4 * g];
            float4 wv = *(const float4*)&ws[k * OUT_DIM + 4 * c];
            acc[0][0] += zv.x * wv.x; acc[0][1] += zv.x * wv.y; acc[0][2] += zv.x * wv.z; acc[0][3] += zv.x * wv.w;
            acc[1][0] += zv.y * wv.x; acc[1][1] += zv.y * wv.y; acc[1][2] += zv.y * wv.z; acc[1][3] += zv.y * wv.w;
            acc[2][0] += zv.z * wv.x; acc[2][1] += zv.z * wv.y; acc[2][2] += zv.z * wv.z; acc[2][3] += zv.z * wv.w;
            acc[3][0] += zv.w * wv.x; acc[3][1] += zv.w * wv.y; acc[3][2] += zv.w * wv.z; acc[3][3] += zv.w * wv.w;
        }
#pragma unroll
        for (int i = 0; i < 4; ++i) {
            int n = nodeBase + 4 * g + i;
            if (n < N_NODES) {
                float di = dinv[n];
                float4 o;
                o.x = acc[i][0] * di;
                o.y = acc[i][1] * di;
                o.z = acc[i][2] * di;
                o.w = acc[i][3] * di;
                *(float4*)&h2p[(size_t)n * OUT_DIM + 4 * c] = o;
            }
        }
    }
}

// one wave per node, lanes 0..39 = out dims
__global__ __launch_bounds__(256) void agg2_kernel(const float* __restrict__ h2p,
                                                   const int* __restrict__ csr,
                                                   const int* __restrict__ row_start,
                                                   const int* __restrict__ cnt,
                                                   const float* __restrict__ dinv,
                                                   const float* __restrict__ b2,
                                                   float* __restrict__ out) {
    int w = blockIdx.x * 4 + (threadIdx.x >> 6);
    int j = threadIdx.x & 63;
    if (w >= N_NODES || j >= OUT_DIM) return;
    int s0 = row_start[w];
    int n  = cnt[w];
    const int* cp = csr + s0;
    float acc = h2p[(size_t)w * OUT_DIM + j];   // self loop
    int k = 0;
    for (; k + 4 <= n; k += 4) {
        int a = cp[k], b = cp[k + 1], c = cp[k + 2], d = cp[k + 3];
        float f0 = h2p[(size_t)a * OUT_DIM + j];
        float f1 = h2p[(size_t)b * OUT_DIM + j];
        float f2 = h2p[(size_t)c * OUT_DIM + j];
        float f3 = h2p[(size_t)d * OUT_DIM + j];
        acc += f0 + f1 + f2 + f3;
    }
    for (; k < n; ++k) acc += h2p[(size_t)cp[k] * OUT_DIM + j];
    out[(size_t)w * OUT_DIM + j] = acc * dinv[w] + b2[j];
}

extern "C" void kernel_launch(void* const* d_in, const int* in_sizes, int n_in,
                              void* d_out, int out_size, void* d_ws, size_t ws_size,
                              hipStream_t stream) {
    const float* x  = (const float*)d_in[0];
    const int*   ei = (const int*)d_in[1];      // [2, E] int32
    const float* W1 = (const float*)d_in[2];
    const float* b1 = (const float*)d_in[3];
    const float* W2 = (const float*)d_in[4];
    const float* b2 = (const float*)d_in[5];
    float* out = (float*)d_out;

    const int* src = ei;
    const int* dst = ei + N_EDGES;

    int* wsi       = (int*)d_ws;
    int* cnt       = wsi;
    int* cursor    = wsi + NPAD;
    int* row_start = wsi + 2 * NPAD;
    int* blockSums = wsi + 3 * NPAD;
    int* csr       = wsi + 3 * NPAD + 128;
    float* dinv    = (float*)(csr + N_EDGES);
    float* h1p     = dinv + NPAD;
    float* z       = h1p + (size_t)N_NODES * HID_DIM;
    float* h2p     = z + (size_t)N_NODES * HID_DIM;

    hipMemsetAsync(d_ws, 0, (size_t)(2 * NPAD) * sizeof(int), stream);

    count_kernel<<<(N_EDGES + 255) / 256, 256, 0, stream>>>(dst, cnt);
    dinv_kernel<<<(N_NODES + 255) / 256, 256, 0, stream>>>(cnt, dinv);

    scan_partial_kernel<<<NB, 256, 0, stream>>>(cnt, row_start, blockSums);
    scan_blocksums_kernel<<<1, 128, 0, stream>>>(blockSums);
    scan_add_kernel<<<(N_NODES + 255) / 256, 256, 0, stream>>>(row_start, blockSums);

    for (int p = 0; p < FILL_PASSES; ++p) {
        int lo = p * FILL_CHUNK;
        int hi = lo + FILL_CHUNK;
        fill_window_kernel<<<(N_EDGES + 255) / 256, 256, 0, stream>>>(src, dst, row_start,
                                                                      cursor, csr, lo, hi);
    }

    gemm1_kernel<<<N_NODES / 32, 256, 0, stream>>>(x, W1, dinv, h1p);

    agg1_kernel<<<(N_NODES + 3) / 4, 256, 0, stream>>>(h1p, csr, row_start, cnt, dinv, b1, z);

    gemm2_kernel<<<(N_NODES + 63) / 64, 256, 0, stream>>>(z, W2, dinv, h2p);

    agg2_kernel<<<(N_NODES + 3) / 4, 256, 0, stream>>>(h2p, csr, row_start, cnt, dinv, b2, out);
}

// Round 5
// 420.935 us; speedup vs baseline: 1.0600x; 1.0600x over previous
//
#include <hip/hip_runtime.h>
#include <math.h>

#define N_NODES 100000
#define N_EDGES 1600000
#define IN_DIM 128
#define HID_DIM 64
#define OUT_DIM 40

#define NPAD 102400
#define SCAN_CHUNK 1024
#define NB ((N_NODES + SCAN_CHUNK - 1) / SCAN_CHUNK)  // 98 blocks

typedef _Float16 f16;
typedef _Float16 f16x2 __attribute__((ext_vector_type(2)));
typedef _Float16 f16x4 __attribute__((ext_vector_type(4)));

// -------- workspace layout (int region first, then fp regions) --------
// ints:   cnt[NPAD] | cursor[NPAD] | row_start[NPAD] | blockSums[128] | csr[N_EDGES]
// floats: dinv[NPAD] | z[N*64]
// f16:    h1p[N*64] | h2p[N*40]
// zeroed per launch: cnt + cursor (2*NPAD ints = 0.8 MB)

__global__ void count_kernel(const int* __restrict__ dst, int* __restrict__ cnt) {
    int e = blockIdx.x * blockDim.x + threadIdx.x;
    if (e < N_EDGES) atomicAdd(&cnt[dst[e]], 1);
}

__global__ void dinv_kernel(const int* __restrict__ cnt, float* __restrict__ dinv) {
    int i = blockIdx.x * blockDim.x + threadIdx.x;
    if (i < N_NODES) dinv[i] = rsqrtf((float)cnt[i] + 1.0f);
}

// exclusive scan, stage 1: per-block (1024 elements, 256 thr x 4) partial scan
__global__ __launch_bounds__(256) void scan_partial_kernel(const int* __restrict__ cnt,
                                                           int* __restrict__ excl,
                                                           int* __restrict__ blockSums) {
    __shared__ int lds[256];
    int base = blockIdx.x * SCAN_CHUNK;
    int t = threadIdx.x;
    int v[4];
    int s = 0;
    for (int k = 0; k < 4; ++k) {
        int idx = base + t * 4 + k;
        int c = (idx < N_NODES) ? cnt[idx] : 0;
        v[k] = s;
        s += c;
    }
    lds[t] = s;
    __syncthreads();
    for (int off = 1; off < 256; off <<= 1) {
        int val = (t >= off) ? lds[t - off] : 0;
        __syncthreads();
        lds[t] += val;
        __syncthreads();
    }
    int thread_excl = (t == 0) ? 0 : lds[t - 1];
    if (t == 255) blockSums[blockIdx.x] = lds[255];
    for (int k = 0; k < 4; ++k) {
        int idx = base + t * 4 + k;
        if (idx < N_NODES) excl[idx] = thread_excl + v[k];
    }
}

__global__ __launch_bounds__(128) void scan_blocksums_kernel(int* __restrict__ blockSums) {
    __shared__ int lds[128];
    int t = threadIdx.x;
    int v = (t < NB) ? blockSums[t] : 0;
    lds[t] = v;
    __syncthreads();
    for (int off = 1; off < 128; off <<= 1) {
        int val = (t >= off) ? lds[t - off] : 0;
        __syncthreads();
        lds[t] += val;
        __syncthreads();
    }
    int excl = (t == 0) ? 0 : lds[t - 1];
    if (t < NB) blockSums[t] = excl;
}

__global__ void scan_add_kernel(int* __restrict__ excl, const int* __restrict__ blockSums) {
    int idx = blockIdx.x * blockDim.x + threadIdx.x;
    if (idx < N_NODES) excl[idx] += blockSums[idx / SCAN_CHUNK];
}

// single-pass CSR fill (R3 config; windowed variant regressed in R4)
__global__ void fill_kernel(const int* __restrict__ src, const int* __restrict__ dst,
                            const int* __restrict__ row_start, int* __restrict__ cursor,
                            int* __restrict__ csr) {
    int e = blockIdx.x * blockDim.x + threadIdx.x;
    if (e < N_EDGES) {
        int d = dst[e];
        int pos = row_start[d] + atomicAdd(&cursor[d], 1);
        csr[pos] = src[e];
    }
}

// ---------------- gemm1: h1p[i][j] = f16( dinv[i] * sum_k x[i][k] * W1[k][j] ) ----------------
#define G1_XS 36
__global__ __launch_bounds__(256) void gemm1_kernel(const float* __restrict__ x,
                                                    const float* __restrict__ W1,
                                                    const float* __restrict__ dinv,
                                                    f16* __restrict__ h1p) {
    __shared__ float ws[IN_DIM * HID_DIM];   // 32 KB
    __shared__ float xT[IN_DIM * G1_XS];     // 18 KB
    int t = threadIdx.x;
    int nodeBase = blockIdx.x * 32;

    const float4* W4 = (const float4*)W1;
    float4* ws4 = (float4*)ws;
#pragma unroll
    for (int i = 0; i < 8; ++i) ws4[t + 256 * i] = W4[t + 256 * i];

    int kg = t & 31;
    int nd = t >> 5;
#pragma unroll
    for (int m = 0; m < 4; ++m) {
        int node = nd + 8 * m;
        const float* xr = x + (size_t)(nodeBase + node) * IN_DIM;
#pragma unroll
        for (int j = 0; j < 4; ++j) {
            xT[(kg + 32 * j) * G1_XS + node] = xr[kg + 32 * j];
        }
    }
    __syncthreads();

    int g = t >> 5;   // node group of 4
    int c = t & 31;   // col group of 2
    float a00 = 0.f, a01 = 0.f, a10 = 0.f, a11 = 0.f;
    float a20 = 0.f, a21 = 0.f, a30 = 0.f, a31 = 0.f;
#pragma unroll 4
    for (int k = 0; k < IN_DIM; ++k) {
        float4 xv = *(const float4*)&xT[k * G1_XS + 4 * g];
        float2 wv = *(const float2*)&ws[k * HID_DIM + 2 * c];
        a00 += xv.x * wv.x; a01 += xv.x * wv.y;
        a10 += xv.y * wv.x; a11 += xv.y * wv.y;
        a20 += xv.z * wv.x; a21 += xv.z * wv.y;
        a30 += xv.w * wv.x; a31 += xv.w * wv.y;
    }
    float r0[4] = {a00, a10, a20, a30};
    float r1[4] = {a01, a11, a21, a31};
#pragma unroll
    for (int i = 0; i < 4; ++i) {
        int n = nodeBase + 4 * g + i;
        float di = dinv[n];
        f16x2 o;
        o.x = (f16)(r0[i] * di);
        o.y = (f16)(r1[i] * di);
        *(f16x2*)&h1p[(size_t)n * HID_DIM + 2 * c] = o;
    }
}

// one wave per node: lanes = 64 hidden dims; gather-sum fp16 neighbor rows (fp32 acc)
__global__ __launch_bounds__(256) void agg1_kernel(const f16* __restrict__ h1p,
                                                   const int* __restrict__ csr,
                                                   const int* __restrict__ row_start,
                                                   const int* __restrict__ cnt,
                                                   const float* __restrict__ dinv,
                                                   const float* __restrict__ b1,
                                                   float* __restrict__ z) {
    int w = blockIdx.x * 4 + (threadIdx.x >> 6);
    int j = threadIdx.x & 63;
    if (w >= N_NODES) return;
    int s0 = row_start[w];
    int n  = cnt[w];
    const int* cp = csr + s0;
    float acc = (float)h1p[(size_t)w * HID_DIM + j];   // self loop
    int k = 0;
    for (; k + 4 <= n; k += 4) {
        int a = cp[k], b = cp[k + 1], c = cp[k + 2], d = cp[k + 3];
        float f0 = (float)h1p[(size_t)a * HID_DIM + j];
        float f1 = (float)h1p[(size_t)b * HID_DIM + j];
        float f2 = (float)h1p[(size_t)c * HID_DIM + j];
        float f3 = (float)h1p[(size_t)d * HID_DIM + j];
        acc += f0 + f1 + f2 + f3;
    }
    for (; k < n; ++k) acc += (float)h1p[(size_t)cp[k] * HID_DIM + j];
    float v = acc * dinv[w] + b1[j];
    z[(size_t)w * HID_DIM + j] = v > 0.f ? v : 0.f;
}

// ---------------- gemm2: h2p[i][j] = f16( dinv[i] * sum_k z[i][k] * W2[k][j] ) ----------------
#define G2_ZS 68
__global__ __launch_bounds__(256) void gemm2_kernel(const float* __restrict__ z,
                                                    const float* __restrict__ W2,
                                                    const float* __restrict__ dinv,
                                                    f16* __restrict__ h2p) {
    __shared__ float ws[HID_DIM * OUT_DIM];  // 2560 floats
    __shared__ float zT[HID_DIM * G2_ZS];    // 4352 floats
    int t = threadIdx.x;
    int nodeBase = blockIdx.x * 64;

    const float4* W4 = (const float4*)W2;
    float4* ws4 = (float4*)ws;
    for (int i = t; i < (HID_DIM * OUT_DIM) / 4; i += 256) ws4[i] = W4[i];

    int kg = t & 31;
    int nd = t >> 5;
#pragma unroll
    for (int m = 0; m < 8; ++m) {
        int node = nd + 8 * m;
        int n = nodeBase + node;
        float v0 = 0.f, v1 = 0.f;
        if (n < N_NODES) {
            const float* zr = z + (size_t)n * HID_DIM;
            v0 = zr[kg];
            v1 = zr[kg + 32];
        }
        zT[kg * G2_ZS + node] = v0;
        zT[(kg + 32) * G2_ZS + node] = v1;
    }
    __syncthreads();

    int g = t >> 4;   // node group of 4
    int c = t & 15;   // col group of 4; active c<10
    if (c < 10) {
        float acc[4][4] = {};
#pragma unroll 4
        for (int k = 0; k < HID_DIM; ++k) {
            float4 zv = *(const float4*)&zT[k * G2_ZS + 4 * g];
            float4 wv = *(const float4*)&ws[k * OUT_DIM + 4 * c];
            acc[0][0] += zv.x * wv.x; acc[0][1] += zv.x * wv.y; acc[0][2] += zv.x * wv.z; acc[0][3] += zv.x * wv.w;
            acc[1][0] += zv.y * wv.x; acc[1][1] += zv.y * wv.y; acc[1][2] += zv.y * wv.z; acc[1][3] += zv.y * wv.w;
            acc[2][0] += zv.z * wv.x; acc[2][1] += zv.z * wv.y; acc[2][2] += zv.z * wv.z; acc[2][3] += zv.z * wv.w;
            acc[3][0] += zv.w * wv.x; acc[3][1] += zv.w * wv.y; acc[3][2] += zv.w * wv.z; acc[3][3] += zv.w * wv.w;
        }
#pragma unroll
        for (int i = 0; i < 4; ++i) {
            int n = nodeBase + 4 * g + i;
            if (n < N_NODES) {
                float di = dinv[n];
                f16x4 o;
                o.x = (f16)(acc[i][0] * di);
                o.y = (f16)(acc[i][1] * di);
                o.z = (f16)(acc[i][2] * di);
                o.w = (f16)(acc[i][3] * di);
                *(f16x4*)&h2p[(size_t)n * OUT_DIM + 4 * c] = o;
            }
        }
    }
}

// one wave per node, lanes 0..39 = out dims; fp16 gather, fp32 acc
__global__ __launch_bounds__(256) void agg2_kernel(const f16* __restrict__ h2p,
                                                   const int* __restrict__ csr,
                                                   const int* __restrict__ row_start,
                                                   const int* __restrict__ cnt,
                                                   const float* __restrict__ dinv,
                                                   const float* __restrict__ b2,
                                                   float* __restrict__ out) {
    int w = blockIdx.x * 4 + (threadIdx.x >> 6);
    int j = threadIdx.x & 63;
    if (w >= N_NODES || j >= OUT_DIM) return;
    int s0 = row_start[w];
    int n  = cnt[w];
    const int* cp = csr + s0;
    float acc = (float)h2p[(size_t)w * OUT_DIM + j];   // self loop
    int k = 0;
    for (; k + 4 <= n; k += 4) {
        int a = cp[k], b = cp[k + 1], c = cp[k + 2], d = cp[k + 3];
        float f0 = (float)h2p[(size_t)a * OUT_DIM + j];
        float f1 = (float)h2p[(size_t)b * OUT_DIM + j];
        float f2 = (float)h2p[(size_t)c * OUT_DIM + j];
        float f3 = (float)h2p[(size_t)d * OUT_DIM + j];
        acc += f0 + f1 + f2 + f3;
    }
    for (; k < n; ++k) acc += (float)h2p[(size_t)cp[k] * OUT_DIM + j];
    out[(size_t)w * OUT_DIM + j] = acc * dinv[w] + b2[j];
}

extern "C" void kernel_launch(void* const* d_in, const int* in_sizes, int n_in,
                              void* d_out, int out_size, void* d_ws, size_t ws_size,
                              hipStream_t stream) {
    const float* x  = (const float*)d_in[0];
    const int*   ei = (const int*)d_in[1];      // [2, E] int32
    const float* W1 = (const float*)d_in[2];
    const float* b1 = (const float*)d_in[3];
    const float* W2 = (const float*)d_in[4];
    const float* b2 = (const float*)d_in[5];
    float* out = (float*)d_out;

    const int* src = ei;
    const int* dst = ei + N_EDGES;

    int* wsi       = (int*)d_ws;
    int* cnt       = wsi;
    int* cursor    = wsi + NPAD;
    int* row_start = wsi + 2 * NPAD;
    int* blockSums = wsi + 3 * NPAD;
    int* csr       = wsi + 3 * NPAD + 128;
    float* dinv    = (float*)(csr + N_EDGES);
    float* z       = dinv + NPAD;
    f16*   h1p     = (f16*)(z + (size_t)N_NODES * HID_DIM);
    f16*   h2p     = h1p + (size_t)N_NODES * HID_DIM;

    hipMemsetAsync(d_ws, 0, (size_t)(2 * NPAD) * sizeof(int), stream);

    count_kernel<<<(N_EDGES + 255) / 256, 256, 0, stream>>>(dst, cnt);
    dinv_kernel<<<(N_NODES + 255) / 256, 256, 0, stream>>>(cnt, dinv);

    scan_partial_kernel<<<NB, 256, 0, stream>>>(cnt, row_start, blockSums);
    scan_blocksums_kernel<<<1, 128, 0, stream>>>(blockSums);
    scan_add_kernel<<<(N_NODES + 255) / 256, 256, 0, stream>>>(row_start, blockSums);

    fill_kernel<<<(N_EDGES + 255) / 256, 256, 0, stream>>>(src, dst, row_start, cursor, csr);

    gemm1_kernel<<<N_NODES / 32, 256, 0, stream>>>(x, W1, dinv, h1p);

    agg1_kernel<<<(N_NODES + 3) / 4, 256, 0, stream>>>(h1p, csr, row_start, cnt, dinv, b1, z);

    gemm2_kernel<<<(N_NODES + 63) / 64, 256, 0, stream>>>(z, W2, dinv, h2p);

    agg2_kernel<<<(N_NODES + 3) / 4, 256, 0, stream>>>(h2p, csr, row_start, cnt, dinv, b2, out);
}